// Round 7
// baseline (197.289 us; speedup 1.0000x reference)
//
#include <hip/hip_runtime.h>
#include <hip/hip_bf16.h>
#include <math.h>

#define BATCH 16
#define CH    64
#define MM    65536          // 256*256
#define PSTRIDE 4160         // 64*64 gram + 64 sums per partial block
#define SF    68             // f32 LDS row stride in ns kernel

typedef __attribute__((ext_vector_type(8))) short s16x8;
typedef __attribute__((ext_vector_type(4))) float f32x4;

__device__ __forceinline__ unsigned short f2bf(float f) {
    __hip_bfloat16 h = __float2bfloat16(f);          // HW cvt (RNE)
    return __builtin_bit_cast(unsigned short, h);
}
__device__ __forceinline__ float bf2f(unsigned short u) {
    return __builtin_bit_cast(float, (unsigned)u << 16);
}

// ---------------------------------------------------------------------------
// Kernel 1: partial Gram via bf16 MFMA (register-direct, statically indexed).
// WC=1: additionally writes the bf16 conversion of x to xb16 (natural layout)
// with REGULAR stores (L3-allocating), while x itself is read with
// NON-TEMPORAL loads (read-once, don't pollute L3). The 134 MB bf16 copy
// fits Infinity Cache (256 MB) — scale_copy re-reads it instead of the
// 268 MB f32 x that provably doesn't stay resident.
// ---------------------------------------------------------------------------
template <int WC>
__global__ __launch_bounds__(256, 3) void gram_mfma(const float* __restrict__ x,
                                                    float* __restrict__ part,
                                                    unsigned short* __restrict__ xb16,
                                                    int nchunk, int chunk_m) {
    int blk = blockIdx.x;
    int b = blk / nchunk, chunk = blk - b * nchunk;
    int t = threadIdx.x, w = t >> 6, l = t & 63;
    int lr = l & 15, lg = l >> 4;
    int mwave = chunk_m >> 2;          // m per wave
    int nck = mwave >> 5;              // 32-m chunks per wave (always even)

    const float* xw = x + (size_t)b * CH * MM + (size_t)chunk * chunk_m +
                      (size_t)w * mwave + lg * 8;
    const float* rp0 = xw + (size_t)(lr)      * MM;
    const float* rp1 = xw + (size_t)(16 + lr) * MM;
    const float* rp2 = xw + (size_t)(32 + lr) * MM;
    const float* rp3 = xw + (size_t)(48 + lr) * MM;
    unsigned short* cp0 = xb16 + (size_t)(rp0 - x);
    unsigned short* cp1 = xb16 + (size_t)(rp1 - x);
    unsigned short* cp2 = xb16 + (size_t)(rp2 - x);
    unsigned short* cp3 = xb16 + (size_t)(rp3 - x);

    f32x4 acc[10];
    f32x4 accs[4];                     // ones-MFMA channel-sum accumulators
    const f32x4 zero = {0.f, 0.f, 0.f, 0.f};
#pragma unroll
    for (int i = 0; i < 10; ++i) acc[i] = zero;
#pragma unroll
    for (int i = 0; i < 4; ++i) accs[i] = zero;

    s16x8 ones;
    {
        unsigned short* op1 = (unsigned short*)&ones;
#pragma unroll
        for (int i = 0; i < 8; ++i) op1[i] = 0x3F80;   // bf16 1.0
    }

    f32x4 A0, A1, A2, A3, A4, A5, A6, A7;
    f32x4 B0, B1, B2, B3, B4, B5, B6, B7;

#define LOAD8(P, o) do {                                                      \
        P##0 = __builtin_nontemporal_load(reinterpret_cast<const f32x4*>(rp0 + (o)));     \
        P##1 = __builtin_nontemporal_load(reinterpret_cast<const f32x4*>(rp0 + (o) + 4)); \
        P##2 = __builtin_nontemporal_load(reinterpret_cast<const f32x4*>(rp1 + (o)));     \
        P##3 = __builtin_nontemporal_load(reinterpret_cast<const f32x4*>(rp1 + (o) + 4)); \
        P##4 = __builtin_nontemporal_load(reinterpret_cast<const f32x4*>(rp2 + (o)));     \
        P##5 = __builtin_nontemporal_load(reinterpret_cast<const f32x4*>(rp2 + (o) + 4)); \
        P##6 = __builtin_nontemporal_load(reinterpret_cast<const f32x4*>(rp3 + (o)));     \
        P##7 = __builtin_nontemporal_load(reinterpret_cast<const f32x4*>(rp3 + (o) + 4)); \
    } while (0)

#define CVT_ROW(va, vb, fr) do {                                              \
        unsigned short* fp = (unsigned short*)&(fr);                          \
        fp[0] = f2bf((va)[0]); fp[1] = f2bf((va)[1]);                         \
        fp[2] = f2bf((va)[2]); fp[3] = f2bf((va)[3]);                         \
        fp[4] = f2bf((vb)[0]); fp[5] = f2bf((vb)[1]);                         \
        fp[6] = f2bf((vb)[2]); fp[7] = f2bf((vb)[3]);                         \
    } while (0)

#define COMPUTE(P, o) do {                                                    \
        s16x8 fr0, fr1, fr2, fr3;                                             \
        CVT_ROW(P##0, P##1, fr0);                                             \
        CVT_ROW(P##2, P##3, fr1);                                             \
        CVT_ROW(P##4, P##5, fr2);                                             \
        CVT_ROW(P##6, P##7, fr3);                                             \
        if (WC) {                                                             \
            *reinterpret_cast<s16x8*>(cp0 + (o)) = fr0;                       \
            *reinterpret_cast<s16x8*>(cp1 + (o)) = fr1;                       \
            *reinterpret_cast<s16x8*>(cp2 + (o)) = fr2;                       \
            *reinterpret_cast<s16x8*>(cp3 + (o)) = fr3;                       \
        }                                                                     \
        acc[0] = __builtin_amdgcn_mfma_f32_16x16x32_bf16(fr0, fr0, acc[0], 0, 0, 0); \
        acc[1] = __builtin_amdgcn_mfma_f32_16x16x32_bf16(fr0, fr1, acc[1], 0, 0, 0); \
        acc[2] = __builtin_amdgcn_mfma_f32_16x16x32_bf16(fr0, fr2, acc[2], 0, 0, 0); \
        acc[3] = __builtin_amdgcn_mfma_f32_16x16x32_bf16(fr0, fr3, acc[3], 0, 0, 0); \
        acc[4] = __builtin_amdgcn_mfma_f32_16x16x32_bf16(fr1, fr1, acc[4], 0, 0, 0); \
        acc[5] = __builtin_amdgcn_mfma_f32_16x16x32_bf16(fr1, fr2, acc[5], 0, 0, 0); \
        acc[6] = __builtin_amdgcn_mfma_f32_16x16x32_bf16(fr1, fr3, acc[6], 0, 0, 0); \
        acc[7] = __builtin_amdgcn_mfma_f32_16x16x32_bf16(fr2, fr2, acc[7], 0, 0, 0); \
        acc[8] = __builtin_amdgcn_mfma_f32_16x16x32_bf16(fr2, fr3, acc[8], 0, 0, 0); \
        acc[9] = __builtin_amdgcn_mfma_f32_16x16x32_bf16(fr3, fr3, acc[9], 0, 0, 0); \
        accs[0] = __builtin_amdgcn_mfma_f32_16x16x32_bf16(ones, fr0, accs[0], 0, 0, 0); \
        accs[1] = __builtin_amdgcn_mfma_f32_16x16x32_bf16(ones, fr1, accs[1], 0, 0, 0); \
        accs[2] = __builtin_amdgcn_mfma_f32_16x16x32_bf16(ones, fr2, accs[2], 0, 0, 0); \
        accs[3] = __builtin_amdgcn_mfma_f32_16x16x32_bf16(ones, fr3, accs[3], 0, 0, 0); \
    } while (0)

    LOAD8(A, 0);
    for (int c = 0; c < nck; c += 2) {
        LOAD8(B, (c + 1) * 32);
        COMPUTE(A, c * 32);
        if (c + 2 < nck) LOAD8(A, (c + 2) * 32);
        COMPUTE(B, (c + 1) * 32);
    }

#define UIDX(i, j) ((i) * 4 + (j) - ((i) * ((i) + 1)) / 2)

    // cross-wave reduction via LDS (only upper tiles stored)
    __shared__ float xs[64 * 65];
    __shared__ float csum[64];
    for (int ww = 0; ww < 4; ++ww) {
        if (w == ww) {
#pragma unroll
            for (int i = 0; i < 4; ++i)
#pragma unroll
                for (int j = 0; j < 4; ++j)
                    if (i <= j) {
#pragma unroll
                        for (int jj = 0; jj < 4; ++jj) {
                            int r = i * 16 + lg * 4 + jj, cc = j * 16 + lr;
                            float v = acc[UIDX(i, j)][jj];
                            if (ww == 0) xs[r * 65 + cc] = v;
                            else         xs[r * 65 + cc] += v;
                        }
                    }
            if (l < 16) {
                if (ww == 0) {
                    csum[l]      = accs[0][0]; csum[16 + l] = accs[1][0];
                    csum[32 + l] = accs[2][0]; csum[48 + l] = accs[3][0];
                } else {
                    csum[l]      += accs[0][0]; csum[16 + l] += accs[1][0];
                    csum[32 + l] += accs[2][0]; csum[48 + l] += accs[3][0];
                }
            }
        }
        __syncthreads();
    }

    float* op = part + (size_t)blk * PSTRIDE;
#pragma unroll
    for (int rix = 0; rix < 16; ++rix) {
        int e = t + rix * 256;
        int r = e >> 6, cc = e & 63;
        float v = ((r >> 4) > (cc >> 4)) ? xs[cc * 65 + r] : xs[r * 65 + cc];
        __builtin_nontemporal_store(v, op + e);
    }
    if (t < 64) __builtin_nontemporal_store(csum[t], op + 4096 + t);
}

// ---------------------------------------------------------------------------
// Kernel 1b: reduce nchunk partials -> one 4160-float block per batch
// ---------------------------------------------------------------------------
__global__ __launch_bounds__(256) void reduce_parts(const float* __restrict__ part,
                                                    float* __restrict__ red,
                                                    int nchunk) {
    int b = blockIdx.y;
    int i = blockIdx.x * 256 + threadIdx.x;      // float4 index, 1040 total
    if (i >= PSTRIDE / 4) return;
    const f32x4* p = reinterpret_cast<const f32x4*>(part + (size_t)b * nchunk * PSTRIDE) + i;
    f32x4 s = {0.f, 0.f, 0.f, 0.f};
    for (int ch = 0; ch < nchunk; ++ch) {
        f32x4 v = __builtin_nontemporal_load(p + (size_t)ch * (PSTRIDE / 4));
        s += v;
    }
    reinterpret_cast<f32x4*>(red + (size_t)b * PSTRIDE)[i] = s;
}

// ---------------------------------------------------------------------------
// Kernel 2: cov -> Newton-Schulz(5) -> FC -> att.  (validated round 6:
// 8 matmuls + 6-step symmetric matvec chain for the final column sums)
// ---------------------------------------------------------------------------
__device__ __forceinline__ void cvt_store(const float* __restrict__ M, int row,
                                          int col, unsigned short* Hp,
                                          unsigned short* Lp) {
    float4 v = *reinterpret_cast<const float4*>(M + row * SF + col);
    ushort4 h, lo;
    h.x = f2bf(v.x); lo.x = f2bf(v.x - bf2f(h.x));
    h.y = f2bf(v.y); lo.y = f2bf(v.y - bf2f(h.y));
    h.z = f2bf(v.z); lo.z = f2bf(v.z - bf2f(h.z));
    h.w = f2bf(v.w); lo.w = f2bf(v.w - bf2f(h.w));
    int byte = (row * 128 + col * 2) ^ ((row & 7) << 4);
    *reinterpret_cast<ushort4*>(reinterpret_cast<char*>(Hp) + byte) = h;
    *reinterpret_cast<ushort4*>(reinterpret_cast<char*>(Lp) + byte) = lo;
}

template <int EPI>   // 0: C=acc   1: C = (r==c?1.5:0) - 0.5*acc
__device__ __forceinline__ void mm64(const float* __restrict__ A,
                                     const float* __restrict__ B,
                                     float* __restrict__ C,
                                     unsigned short* AHp, unsigned short* ALp,
                                     unsigned short* BHp, unsigned short* BLp,
                                     int t) {
    int w = t >> 6, l = t & 63, lg = l >> 4, lr = l & 15;
    __syncthreads();                       // operands (f32) ready
#pragma unroll
    for (int r = 0; r < 4; ++r) {
        int e4 = t + r * 256;              // 1024 float4 = 4096 elements
        int row = e4 >> 4;                 // 16 float4 per row
        int col = (e4 & 15) << 2;
        cvt_store(A, row, col, AHp, ALp);
        cvt_store(B, row, col, BHp, BLp);
    }
    __syncthreads();
    f32x4 acc[4];
    const f32x4 zero = {0.f, 0.f, 0.f, 0.f};
#pragma unroll
    for (int i = 0; i < 4; ++i) acc[i] = zero;
    int arow = w * 16 + lr;
#pragma unroll
    for (int kk = 0; kk < 2; ++kk) {
        int kbyte = kk * 64 + lg * 16;
        int abyte = (arow * 128 + kbyte) ^ ((arow & 7) << 4);
        s16x8 ah = *reinterpret_cast<const s16x8*>(reinterpret_cast<const char*>(AHp) + abyte);
        s16x8 al = *reinterpret_cast<const s16x8*>(reinterpret_cast<const char*>(ALp) + abyte);
#pragma unroll
        for (int ct = 0; ct < 4; ++ct) {
            int brow = ct * 16 + lr;
            int bbyte = (brow * 128 + kbyte) ^ ((brow & 7) << 4);
            s16x8 bh = *reinterpret_cast<const s16x8*>(reinterpret_cast<const char*>(BHp) + bbyte);
            s16x8 bl = *reinterpret_cast<const s16x8*>(reinterpret_cast<const char*>(BLp) + bbyte);
            acc[ct] = __builtin_amdgcn_mfma_f32_16x16x32_bf16(ah, bh, acc[ct], 0, 0, 0);
            acc[ct] = __builtin_amdgcn_mfma_f32_16x16x32_bf16(ah, bl, acc[ct], 0, 0, 0);
            acc[ct] = __builtin_amdgcn_mfma_f32_16x16x32_bf16(al, bh, acc[ct], 0, 0, 0);
        }
    }
#pragma unroll
    for (int ct = 0; ct < 4; ++ct)
#pragma unroll
        for (int j = 0; j < 4; ++j) {
            int r = w * 16 + lg * 4 + j, c = ct * 16 + lr;
            float v = acc[ct][j];
            if (EPI == 1) v = (r == c ? 1.5f : 0.f) - 0.5f * v;
            C[r * SF + c] = v;
        }
    __syncthreads();                       // result visible
}

// dst[i] = sum_j M[j][i] * (src ? src[j] : 1)   (M symmetric)
__device__ __forceinline__ void mv64(float* __restrict__ dst,
                                     const float* __restrict__ M,
                                     const float* __restrict__ src,
                                     float* __restrict__ mvp, int t) {
    int i = t & 63, q = t >> 6;
    float p = 0.f;
#pragma unroll
    for (int jj = 0; jj < 16; ++jj) {
        int j = q * 16 + jj;
        float s = src ? src[j] : 1.f;
        p = fmaf(M[j * SF + i], s, p);
    }
    mvp[q * 64 + i] = p;
    __syncthreads();
    if (t < 64) dst[t] = (mvp[t] + mvp[64 + t]) + (mvp[128 + t] + mvp[192 + t]);
    __syncthreads();
}

__global__ __launch_bounds__(256) void ns_att(const float* __restrict__ red,
                                              const float* __restrict__ w1,
                                              const float* __restrict__ b1,
                                              const float* __restrict__ w2,
                                              const float* __restrict__ b2,
                                              float* __restrict__ att) {
    __shared__ float BUF[5][64 * SF];
    __shared__ unsigned short AH[64 * 64], AL[64 * 64], BH[64 * 64], BL[64 * 64];
    __shared__ float sv[64], u4s[64], vecA[64], vecB[64];
    __shared__ float mvp[256];
    __shared__ float hid8[8];
    __shared__ float scal[2];

    int b = blockIdx.x, t = threadIdx.x;
    const float* pb = red + (size_t)b * PSTRIDE;

    if (t < 64) sv[t] = pb[4096 + t];
    __syncthreads();

    // cov (unscaled) -> BUF0
    const float invM = 1.0f / (float)MM;
    const float invM2 = invM * invM;
#pragma unroll
    for (int r = 0; r < 4; ++r) {
        int e4 = t + r * 256;
        int row = e4 >> 4;
        int col = (e4 & 15) << 2;
        float4 g = *(reinterpret_cast<const float4*>(pb) + e4);
        float sr = sv[row] * invM2;
        BUF[0][row * SF + col]     = g.x * invM - sr * sv[col];
        BUF[0][row * SF + col + 1] = g.y * invM - sr * sv[col + 1];
        BUF[0][row * SF + col + 2] = g.z * invM - sr * sv[col + 2];
        BUF[0][row * SF + col + 3] = g.w * invM - sr * sv[col + 3];
    }
    __syncthreads();

    // trace via wave-0 shuffle reduction
    if (t < 64) {
        float d = BUF[0][t * SF + t];
#pragma unroll
        for (int m = 1; m < 64; m <<= 1) d += __shfl_xor(d, m);
        if (t == 0) { scal[0] = 1.0f / d; scal[1] = sqrtf(d); }
    }
    __syncthreads();
    float itr = scal[0];

    // A = cov/tr -> BUF0 ; ZY0 = 1.5I - 0.5A -> BUF1  (fused pass)
#pragma unroll
    for (int rr = 0; rr < 16; ++rr) {
        int e = t + rr * 256;
        int r = e >> 6, c = e & 63;
        float a = BUF[0][r * SF + c] * itr;
        BUF[0][r * SF + c] = a;
        BUF[1][r * SF + c] = (r == c ? 1.5f : 0.f) - 0.5f * a;
    }

    // 8 matmuls (Z1 = ZY0 = BUF1)
    mm64<0>(BUF[0], BUF[1], BUF[2], AH, AL, BH, BL, t);  // Y1 = A@ZY0
    mm64<1>(BUF[1], BUF[2], BUF[3], AH, AL, BH, BL, t);  // ZY1 = 1.5I-0.5 Z1@Y1
    mm64<0>(BUF[2], BUF[3], BUF[4], AH, AL, BH, BL, t);  // Y2 = Y1@ZY1
    mm64<0>(BUF[3], BUF[1], BUF[0], AH, AL, BH, BL, t);  // Z2 = ZY1@Z1
    mm64<1>(BUF[0], BUF[4], BUF[1], AH, AL, BH, BL, t);  // ZY2 = 1.5I-0.5 Z2@Y2
    mm64<0>(BUF[4], BUF[1], BUF[2], AH, AL, BH, BL, t);  // Y3 = Y2@ZY2
    mm64<0>(BUF[1], BUF[0], BUF[3], AH, AL, BH, BL, t);  // Z3 = ZY2@Z2
    mm64<1>(BUF[3], BUF[2], BUF[0], AH, AL, BH, BL, t);  // ZY3 = 1.5I-0.5 Z3@Y3
    // live: Y3 = BUF2, Z3 = BUF3, ZY3 = BUF0

    mv64(vecA, BUF[2], nullptr, mvp, t);   // u3 = 1^T Y3
    mv64(u4s,  BUF[0], vecA,    mvp, t);   // u4 = u3@ZY3
    mv64(vecA, BUF[0], u4s,     mvp, t);   // p  = u4@ZY3
    mv64(vecB, BUF[3], vecA,    mvp, t);   // q  = p@Z3    (= u4@Z4)
    mv64(vecA, BUF[2], vecB,    mvp, t);   // r  = q@Y3
    mv64(vecB, BUF[0], vecA,    mvp, t);   // s  = r@ZY3   (= u4@Z4@Y4)

    if (t < 64) sv[t] = (1.5f * u4s[t] - 0.5f * vecB[t]) * scal[1] * (1.0f / 64.0f);
    __syncthreads();
    if (t < 8) {
        float h = b1[t];
        for (int c = 0; c < 64; ++c) h += sv[c] * w1[t * 64 + c];
        hid8[t] = h > 0.f ? h : 0.f;
    }
    __syncthreads();
    if (t < 64) {
        float p = b2[t];
        for (int h = 0; h < 8; ++h) p += hid8[h] * w2[t * 8 + h];
        att[b * 64 + t] = 1.0f / (1.0f + expf(-p));
    }
}

// ---------------------------------------------------------------------------
// Kernel 3a (copy path): out = att * f32(xb16).  xb16 (134 MB) is L3-resident
// (written by gram with regular stores; x reads were nt). Reads 8 B/lane,
// writes 16 B/lane nt.
// ---------------------------------------------------------------------------
__global__ __launch_bounds__(256) void scale_copy(const unsigned short* __restrict__ xc,
                                                  const float* __restrict__ att,
                                                  float* __restrict__ out) {
    const size_t total4 = (size_t)BATCH * CH * MM / 4;
    const size_t stride = (size_t)gridDim.x * blockDim.x;
    f32x4* o4 = reinterpret_cast<f32x4*>(out);
    size_t j = (size_t)blockIdx.x * blockDim.x + threadIdx.x;
    for (; j < total4; j += stride) {
        int bc = (int)(j >> 14);        // MM/4 float4 per channel
        float a = att[bc];
        ushort4 u = *reinterpret_cast<const ushort4*>(xc + 4 * j);
        f32x4 v;
        v[0] = bf2f(u.x) * a;
        v[1] = bf2f(u.y) * a;
        v[2] = bf2f(u.z) * a;
        v[3] = bf2f(u.w) * a;
        __builtin_nontemporal_store(v, o4 + j);
    }
}

// ---------------------------------------------------------------------------
// Kernel 3b (fallback, ws too small): round-6 reversed-traversal scale.
// ---------------------------------------------------------------------------
__global__ __launch_bounds__(256) void scale_out(const float* __restrict__ x,
                                                 const float* __restrict__ att,
                                                 float* __restrict__ out) {
    const size_t total4 = (size_t)BATCH * CH * MM / 4;
    const size_t stride = (size_t)gridDim.x * blockDim.x;
    const f32x4* x4 = reinterpret_cast<const f32x4*>(x);
    f32x4* o4 = reinterpret_cast<f32x4*>(out);
    size_t base = (size_t)(gridDim.x - 1 - blockIdx.x) * blockDim.x + threadIdx.x;
    int niter = (int)(total4 / stride);
    size_t i = base + (size_t)(niter - 1) * stride;
    for (int k = 0; k < niter; ++k) {
        int bc = (int)(i >> 14);
        float a = att[bc];
        f32x4 v = x4[i];
        v *= a;
        __builtin_nontemporal_store(v, o4 + i);
        i -= stride;
    }
}

// ---------------------------------------------------------------------------
extern "C" void kernel_launch(void* const* d_in, const int* in_sizes, int n_in,
                              void* d_out, int out_size, void* d_ws, size_t ws_size,
                              hipStream_t stream) {
    const float* x  = (const float*)d_in[0];
    const float* w1 = (const float*)d_in[1];
    const float* b1 = (const float*)d_in[2];
    const float* w2 = (const float*)d_in[3];
    const float* b2 = (const float*)d_in[4];
    float* out = (float*)d_out;

    const int nchunk = 64;
    const int chunk_m = MM / nchunk;
    const size_t copy_bytes = (size_t)BATCH * CH * MM * 2;          // 134 MB
    const size_t part_bytes = (size_t)BATCH * nchunk * PSTRIDE * 4;
    const size_t red_bytes  = (size_t)BATCH * PSTRIDE * 4;
    const size_t att_bytes  = (size_t)BATCH * CH * 4;

    bool wc = ws_size >= copy_bytes + part_bytes + red_bytes + att_bytes;

    char* wsb = (char*)d_ws;
    unsigned short* xb16 = (unsigned short*)wsb;
    float* part = (float*)(wsb + (wc ? copy_bytes : 0));
    float* red  = (float*)((char*)part + part_bytes);
    float* att  = (float*)((char*)red + red_bytes);

    if (wc) {
        gram_mfma<1><<<BATCH * nchunk, 256, 0, stream>>>(x, part, xb16, nchunk, chunk_m);
    } else {
        gram_mfma<0><<<BATCH * nchunk, 256, 0, stream>>>(x, part, xb16, nchunk, chunk_m);
    }
    reduce_parts<<<dim3((PSTRIDE / 4 + 255) / 256, BATCH), 256, 0, stream>>>(part, red, nchunk);
    ns_att<<<BATCH, 256, 0, stream>>>(red, w1, b1, w2, b2, att);
    if (wc) {
        scale_copy<<<4096, 256, 0, stream>>>(xb16, att, out);
    } else {
        scale_out<<<4096, 256, 0, stream>>>(x, att, out);
    }
}

// Round 8
// 181.749 us; speedup vs baseline: 1.0855x; 1.0855x over previous
//
#include <hip/hip_runtime.h>
#include <hip/hip_bf16.h>
#include <math.h>

#define BATCH 16
#define CH    64
#define MM    65536          // 256*256
#define PSTRIDE 4160         // 64*64 gram + 64 sums per partial block
#define SF    68             // f32 LDS row stride in ns kernel

typedef __attribute__((ext_vector_type(8))) short s16x8;
typedef __attribute__((ext_vector_type(4))) float f32x4;

__device__ __forceinline__ unsigned short f2bf(float f) {
    __hip_bfloat16 h = __float2bfloat16(f);          // HW cvt (RNE)
    return __builtin_bit_cast(unsigned short, h);
}
__device__ __forceinline__ float bf2f(unsigned short u) {
    return __builtin_bit_cast(float, (unsigned)u << 16);
}

// ---------------------------------------------------------------------------
// Kernel 1: partial Gram via bf16 MFMA (register-direct, statically indexed —
// rule #20). Channel sums via ones-fragment MFMAs. launch_bounds (256,4):
// VGPR=72 fits 4 blocks/CU -> 16 waves/CU AND 1024 blocks = exactly one
// dispatch round (kills the 256-block tail that (256,3) had).
// ---------------------------------------------------------------------------
__global__ __launch_bounds__(256, 4) void gram_mfma(const float* __restrict__ x,
                                                    float* __restrict__ part,
                                                    int nchunk, int chunk_m) {
    int blk = blockIdx.x;
    int b = blk / nchunk, chunk = blk - b * nchunk;
    int t = threadIdx.x, w = t >> 6, l = t & 63;
    int lr = l & 15, lg = l >> 4;
    int mwave = chunk_m >> 2;          // m per wave
    int nck = mwave >> 5;              // 32-m chunks per wave (always even)

    const float* xw = x + (size_t)b * CH * MM + (size_t)chunk * chunk_m +
                      (size_t)w * mwave + lg * 8;
    const float* rp0 = xw + (size_t)(lr)      * MM;
    const float* rp1 = xw + (size_t)(16 + lr) * MM;
    const float* rp2 = xw + (size_t)(32 + lr) * MM;
    const float* rp3 = xw + (size_t)(48 + lr) * MM;

    f32x4 acc[10];
    f32x4 accs[4];                     // ones-MFMA channel-sum accumulators
    const f32x4 zero = {0.f, 0.f, 0.f, 0.f};
#pragma unroll
    for (int i = 0; i < 10; ++i) acc[i] = zero;
#pragma unroll
    for (int i = 0; i < 4; ++i) accs[i] = zero;

    s16x8 ones;
    {
        unsigned short* op1 = (unsigned short*)&ones;
#pragma unroll
        for (int i = 0; i < 8; ++i) op1[i] = 0x3F80;   // bf16 1.0
    }

    float4 A0, A1, A2, A3, A4, A5, A6, A7;
    float4 B0, B1, B2, B3, B4, B5, B6, B7;

#define LOAD8(P, o) do {                                                      \
        P##0 = *(const float4*)(rp0 + (o));  P##1 = *(const float4*)(rp0 + (o) + 4); \
        P##2 = *(const float4*)(rp1 + (o));  P##3 = *(const float4*)(rp1 + (o) + 4); \
        P##4 = *(const float4*)(rp2 + (o));  P##5 = *(const float4*)(rp2 + (o) + 4); \
        P##6 = *(const float4*)(rp3 + (o));  P##7 = *(const float4*)(rp3 + (o) + 4); \
    } while (0)

#define CVT_ROW(va, vb, fr) do {                                              \
        unsigned short* fp = (unsigned short*)&(fr);                          \
        fp[0] = f2bf((va).x); fp[1] = f2bf((va).y);                           \
        fp[2] = f2bf((va).z); fp[3] = f2bf((va).w);                           \
        fp[4] = f2bf((vb).x); fp[5] = f2bf((vb).y);                           \
        fp[6] = f2bf((vb).z); fp[7] = f2bf((vb).w);                           \
    } while (0)

#define COMPUTE(P) do {                                                       \
        s16x8 fr0, fr1, fr2, fr3;                                             \
        CVT_ROW(P##0, P##1, fr0);                                             \
        CVT_ROW(P##2, P##3, fr1);                                             \
        CVT_ROW(P##4, P##5, fr2);                                             \
        CVT_ROW(P##6, P##7, fr3);                                             \
        acc[0] = __builtin_amdgcn_mfma_f32_16x16x32_bf16(fr0, fr0, acc[0], 0, 0, 0); \
        acc[1] = __builtin_amdgcn_mfma_f32_16x16x32_bf16(fr0, fr1, acc[1], 0, 0, 0); \
        acc[2] = __builtin_amdgcn_mfma_f32_16x16x32_bf16(fr0, fr2, acc[2], 0, 0, 0); \
        acc[3] = __builtin_amdgcn_mfma_f32_16x16x32_bf16(fr0, fr3, acc[3], 0, 0, 0); \
        acc[4] = __builtin_amdgcn_mfma_f32_16x16x32_bf16(fr1, fr1, acc[4], 0, 0, 0); \
        acc[5] = __builtin_amdgcn_mfma_f32_16x16x32_bf16(fr1, fr2, acc[5], 0, 0, 0); \
        acc[6] = __builtin_amdgcn_mfma_f32_16x16x32_bf16(fr1, fr3, acc[6], 0, 0, 0); \
        acc[7] = __builtin_amdgcn_mfma_f32_16x16x32_bf16(fr2, fr2, acc[7], 0, 0, 0); \
        acc[8] = __builtin_amdgcn_mfma_f32_16x16x32_bf16(fr2, fr3, acc[8], 0, 0, 0); \
        acc[9] = __builtin_amdgcn_mfma_f32_16x16x32_bf16(fr3, fr3, acc[9], 0, 0, 0); \
        accs[0] = __builtin_amdgcn_mfma_f32_16x16x32_bf16(ones, fr0, accs[0], 0, 0, 0); \
        accs[1] = __builtin_amdgcn_mfma_f32_16x16x32_bf16(ones, fr1, accs[1], 0, 0, 0); \
        accs[2] = __builtin_amdgcn_mfma_f32_16x16x32_bf16(ones, fr2, accs[2], 0, 0, 0); \
        accs[3] = __builtin_amdgcn_mfma_f32_16x16x32_bf16(ones, fr3, accs[3], 0, 0, 0); \
    } while (0)

    LOAD8(A, 0);
    for (int c = 0; c < nck; c += 2) {
        LOAD8(B, (c + 1) * 32);
        COMPUTE(A);
        if (c + 2 < nck) LOAD8(A, (c + 2) * 32);
        COMPUTE(B);
    }

#define UIDX(i, j) ((i) * 4 + (j) - ((i) * ((i) + 1)) / 2)

    // cross-wave reduction via LDS (only upper tiles stored)
    __shared__ float xs[64 * 65];
    __shared__ float csum[64];
    for (int ww = 0; ww < 4; ++ww) {
        if (w == ww) {
#pragma unroll
            for (int i = 0; i < 4; ++i)
#pragma unroll
                for (int j = 0; j < 4; ++j)
                    if (i <= j) {
#pragma unroll
                        for (int jj = 0; jj < 4; ++jj) {
                            int r = i * 16 + lg * 4 + jj, cc = j * 16 + lr;
                            float v = acc[UIDX(i, j)][jj];
                            if (ww == 0) xs[r * 65 + cc] = v;
                            else         xs[r * 65 + cc] += v;
                        }
                    }
            if (l < 16) {
                if (ww == 0) {
                    csum[l]      = accs[0][0]; csum[16 + l] = accs[1][0];
                    csum[32 + l] = accs[2][0]; csum[48 + l] = accs[3][0];
                } else {
                    csum[l]      += accs[0][0]; csum[16 + l] += accs[1][0];
                    csum[32 + l] += accs[2][0]; csum[48 + l] += accs[3][0];
                }
            }
        }
        __syncthreads();
    }

    float* op = part + (size_t)blk * PSTRIDE;
#pragma unroll
    for (int rix = 0; rix < 16; ++rix) {
        int e = t + rix * 256;
        int r = e >> 6, cc = e & 63;
        float v = ((r >> 4) > (cc >> 4)) ? xs[cc * 65 + r] : xs[r * 65 + cc];
        __builtin_nontemporal_store(v, op + e);
    }
    if (t < 64) __builtin_nontemporal_store(csum[t], op + 4096 + t);
}

// ---------------------------------------------------------------------------
// Kernel 1b: reduce nchunk partials -> one 4160-float block per batch
// ---------------------------------------------------------------------------
__global__ __launch_bounds__(256) void reduce_parts(const float* __restrict__ part,
                                                    float* __restrict__ red,
                                                    int nchunk) {
    int b = blockIdx.y;
    int i = blockIdx.x * 256 + threadIdx.x;      // float4 index, 1040 total
    if (i >= PSTRIDE / 4) return;
    const f32x4* p = reinterpret_cast<const f32x4*>(part + (size_t)b * nchunk * PSTRIDE) + i;
    f32x4 s = {0.f, 0.f, 0.f, 0.f};
    for (int ch = 0; ch < nchunk; ++ch) {
        f32x4 v = __builtin_nontemporal_load(p + (size_t)ch * (PSTRIDE / 4));
        s += v;
    }
    reinterpret_cast<f32x4*>(red + (size_t)b * PSTRIDE)[i] = s;
}

// ---------------------------------------------------------------------------
// Kernel 2: cov -> Newton-Schulz(5) -> FC -> att.  (validated round 6:
// 8 matmuls + 6-step symmetric matvec chain for the final column sums)
// ---------------------------------------------------------------------------
__device__ __forceinline__ void cvt_store(const float* __restrict__ M, int row,
                                          int col, unsigned short* Hp,
                                          unsigned short* Lp) {
    float4 v = *reinterpret_cast<const float4*>(M + row * SF + col);
    ushort4 h, lo;
    h.x = f2bf(v.x); lo.x = f2bf(v.x - bf2f(h.x));
    h.y = f2bf(v.y); lo.y = f2bf(v.y - bf2f(h.y));
    h.z = f2bf(v.z); lo.z = f2bf(v.z - bf2f(h.z));
    h.w = f2bf(v.w); lo.w = f2bf(v.w - bf2f(h.w));
    int byte = (row * 128 + col * 2) ^ ((row & 7) << 4);
    *reinterpret_cast<ushort4*>(reinterpret_cast<char*>(Hp) + byte) = h;
    *reinterpret_cast<ushort4*>(reinterpret_cast<char*>(Lp) + byte) = lo;
}

template <int EPI>   // 0: C=acc   1: C = (r==c?1.5:0) - 0.5*acc
__device__ __forceinline__ void mm64(const float* __restrict__ A,
                                     const float* __restrict__ B,
                                     float* __restrict__ C,
                                     unsigned short* AHp, unsigned short* ALp,
                                     unsigned short* BHp, unsigned short* BLp,
                                     int t) {
    int w = t >> 6, l = t & 63, lg = l >> 4, lr = l & 15;
    __syncthreads();                       // operands (f32) ready
#pragma unroll
    for (int r = 0; r < 4; ++r) {
        int e4 = t + r * 256;              // 1024 float4 = 4096 elements
        int row = e4 >> 4;                 // 16 float4 per row
        int col = (e4 & 15) << 2;
        cvt_store(A, row, col, AHp, ALp);
        cvt_store(B, row, col, BHp, BLp);
    }
    __syncthreads();
    f32x4 acc[4];
    const f32x4 zero = {0.f, 0.f, 0.f, 0.f};
#pragma unroll
    for (int i = 0; i < 4; ++i) acc[i] = zero;
    int arow = w * 16 + lr;
#pragma unroll
    for (int kk = 0; kk < 2; ++kk) {
        int kbyte = kk * 64 + lg * 16;
        int abyte = (arow * 128 + kbyte) ^ ((arow & 7) << 4);
        s16x8 ah = *reinterpret_cast<const s16x8*>(reinterpret_cast<const char*>(AHp) + abyte);
        s16x8 al = *reinterpret_cast<const s16x8*>(reinterpret_cast<const char*>(ALp) + abyte);
#pragma unroll
        for (int ct = 0; ct < 4; ++ct) {
            int brow = ct * 16 + lr;
            int bbyte = (brow * 128 + kbyte) ^ ((brow & 7) << 4);
            s16x8 bh = *reinterpret_cast<const s16x8*>(reinterpret_cast<const char*>(BHp) + bbyte);
            s16x8 bl = *reinterpret_cast<const s16x8*>(reinterpret_cast<const char*>(BLp) + bbyte);
            acc[ct] = __builtin_amdgcn_mfma_f32_16x16x32_bf16(ah, bh, acc[ct], 0, 0, 0);
            acc[ct] = __builtin_amdgcn_mfma_f32_16x16x32_bf16(ah, bl, acc[ct], 0, 0, 0);
            acc[ct] = __builtin_amdgcn_mfma_f32_16x16x32_bf16(al, bh, acc[ct], 0, 0, 0);
        }
    }
#pragma unroll
    for (int ct = 0; ct < 4; ++ct)
#pragma unroll
        for (int j = 0; j < 4; ++j) {
            int r = w * 16 + lg * 4 + j, c = ct * 16 + lr;
            float v = acc[ct][j];
            if (EPI == 1) v = (r == c ? 1.5f : 0.f) - 0.5f * v;
            C[r * SF + c] = v;
        }
    __syncthreads();                       // result visible
}

// dst[i] = sum_j M[j][i] * (src ? src[j] : 1)   (M symmetric)
__device__ __forceinline__ void mv64(float* __restrict__ dst,
                                     const float* __restrict__ M,
                                     const float* __restrict__ src,
                                     float* __restrict__ mvp, int t) {
    int i = t & 63, q = t >> 6;
    float p = 0.f;
#pragma unroll
    for (int jj = 0; jj < 16; ++jj) {
        int j = q * 16 + jj;
        float s = src ? src[j] : 1.f;
        p = fmaf(M[j * SF + i], s, p);
    }
    mvp[q * 64 + i] = p;
    __syncthreads();
    if (t < 64) dst[t] = (mvp[t] + mvp[64 + t]) + (mvp[128 + t] + mvp[192 + t]);
    __syncthreads();
}

__global__ __launch_bounds__(256) void ns_att(const float* __restrict__ red,
                                              const float* __restrict__ w1,
                                              const float* __restrict__ b1,
                                              const float* __restrict__ w2,
                                              const float* __restrict__ b2,
                                              float* __restrict__ att) {
    __shared__ float BUF[5][64 * SF];
    __shared__ unsigned short AH[64 * 64], AL[64 * 64], BH[64 * 64], BL[64 * 64];
    __shared__ float sv[64], u4s[64], vecA[64], vecB[64];
    __shared__ float mvp[256];
    __shared__ float hid8[8];
    __shared__ float scal[2];

    int b = blockIdx.x, t = threadIdx.x;
    const float* pb = red + (size_t)b * PSTRIDE;

    if (t < 64) sv[t] = pb[4096 + t];
    __syncthreads();

    // cov (unscaled) -> BUF0
    const float invM = 1.0f / (float)MM;
    const float invM2 = invM * invM;
#pragma unroll
    for (int r = 0; r < 4; ++r) {
        int e4 = t + r * 256;
        int row = e4 >> 4;
        int col = (e4 & 15) << 2;
        float4 g = *(reinterpret_cast<const float4*>(pb) + e4);
        float sr = sv[row] * invM2;
        BUF[0][row * SF + col]     = g.x * invM - sr * sv[col];
        BUF[0][row * SF + col + 1] = g.y * invM - sr * sv[col + 1];
        BUF[0][row * SF + col + 2] = g.z * invM - sr * sv[col + 2];
        BUF[0][row * SF + col + 3] = g.w * invM - sr * sv[col + 3];
    }
    __syncthreads();

    // trace via wave-0 shuffle reduction
    if (t < 64) {
        float d = BUF[0][t * SF + t];
#pragma unroll
        for (int m = 1; m < 64; m <<= 1) d += __shfl_xor(d, m);
        if (t == 0) { scal[0] = 1.0f / d; scal[1] = sqrtf(d); }
    }
    __syncthreads();
    float itr = scal[0];

    // A = cov/tr -> BUF0 ; ZY0 = 1.5I - 0.5A -> BUF1  (fused pass)
#pragma unroll
    for (int rr = 0; rr < 16; ++rr) {
        int e = t + rr * 256;
        int r = e >> 6, c = e & 63;
        float a = BUF[0][r * SF + c] * itr;
        BUF[0][r * SF + c] = a;
        BUF[1][r * SF + c] = (r == c ? 1.5f : 0.f) - 0.5f * a;
    }

    // 8 matmuls (Z1 = ZY0 = BUF1)
    mm64<0>(BUF[0], BUF[1], BUF[2], AH, AL, BH, BL, t);  // Y1 = A@ZY0
    mm64<1>(BUF[1], BUF[2], BUF[3], AH, AL, BH, BL, t);  // ZY1 = 1.5I-0.5 Z1@Y1
    mm64<0>(BUF[2], BUF[3], BUF[4], AH, AL, BH, BL, t);  // Y2 = Y1@ZY1
    mm64<0>(BUF[3], BUF[1], BUF[0], AH, AL, BH, BL, t);  // Z2 = ZY1@Z1
    mm64<1>(BUF[0], BUF[4], BUF[1], AH, AL, BH, BL, t);  // ZY2 = 1.5I-0.5 Z2@Y2
    mm64<0>(BUF[4], BUF[1], BUF[2], AH, AL, BH, BL, t);  // Y3 = Y2@ZY2
    mm64<0>(BUF[1], BUF[0], BUF[3], AH, AL, BH, BL, t);  // Z3 = ZY2@Z2
    mm64<1>(BUF[3], BUF[2], BUF[0], AH, AL, BH, BL, t);  // ZY3 = 1.5I-0.5 Z3@Y3
    // live: Y3 = BUF2, Z3 = BUF3, ZY3 = BUF0

    mv64(vecA, BUF[2], nullptr, mvp, t);   // u3 = 1^T Y3
    mv64(u4s,  BUF[0], vecA,    mvp, t);   // u4 = u3@ZY3
    mv64(vecA, BUF[0], u4s,     mvp, t);   // p  = u4@ZY3
    mv64(vecB, BUF[3], vecA,    mvp, t);   // q  = p@Z3    (= u4@Z4)
    mv64(vecA, BUF[2], vecB,    mvp, t);   // r  = q@Y3
    mv64(vecB, BUF[0], vecA,    mvp, t);   // s  = r@ZY3   (= u4@Z4@Y4)

    if (t < 64) sv[t] = (1.5f * u4s[t] - 0.5f * vecB[t]) * scal[1] * (1.0f / 64.0f);
    __syncthreads();
    if (t < 8) {
        float h = b1[t];
        for (int c = 0; c < 64; ++c) h += sv[c] * w1[t * 64 + c];
        hid8[t] = h > 0.f ? h : 0.f;
    }
    __syncthreads();
    if (t < 64) {
        float p = b2[t];
        for (int h = 0; h < 8; ++h) p += hid8[h] * w2[t * 8 + h];
        att[b * 64 + t] = 1.0f / (1.0f + expf(-p));
    }
}

// ---------------------------------------------------------------------------
// Kernel 3: out = att*x.  Reversed block-granularity traversal (L3 holds the
// tail of x after gram's forward sweep); nt stores; unroll-4 for 4 loads in
// flight per thread.
// ---------------------------------------------------------------------------
__global__ __launch_bounds__(256) void scale_out(const float* __restrict__ x,
                                                 const float* __restrict__ att,
                                                 float* __restrict__ out) {
    const size_t total4 = (size_t)BATCH * CH * MM / 4;    // 16,777,216
    const size_t stride = (size_t)gridDim.x * blockDim.x; // 1,048,576 (16 iters)
    const f32x4* x4 = reinterpret_cast<const f32x4*>(x);
    f32x4* o4 = reinterpret_cast<f32x4*>(out);
    size_t base = (size_t)(gridDim.x - 1 - blockIdx.x) * blockDim.x + threadIdx.x;
    int niter = (int)(total4 / stride);
    size_t i = base + (size_t)(niter - 1) * stride;
#pragma unroll 4
    for (int k = 0; k < niter; ++k) {
        int bc = (int)(i >> 14);        // MM/4 = 16384 float4 per channel
        float a = att[bc];
        f32x4 v = x4[i];
        v *= a;
        __builtin_nontemporal_store(v, o4 + i);
        i -= stride;
    }
}

// ---------------------------------------------------------------------------
extern "C" void kernel_launch(void* const* d_in, const int* in_sizes, int n_in,
                              void* d_out, int out_size, void* d_ws, size_t ws_size,
                              hipStream_t stream) {
    const float* x  = (const float*)d_in[0];
    const float* w1 = (const float*)d_in[1];
    const float* b1 = (const float*)d_in[2];
    const float* w2 = (const float*)d_in[3];
    const float* b2 = (const float*)d_in[4];
    float* out = (float*)d_out;
    float* ws  = (float*)d_ws;

    int nchunk = 64;
    for (;;) {
        size_t need = ((size_t)BATCH * nchunk * PSTRIDE + (size_t)BATCH * PSTRIDE +
                       (size_t)BATCH * CH) * sizeof(float);
        if (need <= ws_size || nchunk == 1) break;
        nchunk >>= 1;
    }
    int chunk_m = MM / nchunk;

    float* part = ws;
    float* red  = ws + (size_t)BATCH * nchunk * PSTRIDE;
    float* att  = red + (size_t)BATCH * PSTRIDE;

    gram_mfma<<<BATCH * nchunk, 256, 0, stream>>>(x, part, nchunk, chunk_m);
    reduce_parts<<<dim3((PSTRIDE / 4 + 255) / 256, BATCH), 256, 0, stream>>>(part, red, nchunk);
    ns_att<<<BATCH, 256, 0, stream>>>(red, w1, b1, w2, b2, att);
    scale_out<<<4096, 256, 0, stream>>>(x, att, out);
}

// Round 9
// 169.663 us; speedup vs baseline: 1.1628x; 1.0712x over previous
//
#include <hip/hip_runtime.h>
#include <hip/hip_bf16.h>
#include <math.h>

#define BATCH 16
#define CH    64
#define MM    65536          // 256*256
#define PSTRIDE 4160         // 64*64 gram + 64 sums per partial block
#define SF    68             // f32 LDS row stride in ns kernel

typedef __attribute__((ext_vector_type(8))) short s16x8;
typedef __attribute__((ext_vector_type(4))) float f32x4;

__device__ __forceinline__ unsigned short f2bf(float f) {
    __hip_bfloat16 h = __float2bfloat16(f);          // HW cvt (RNE)
    return __builtin_bit_cast(unsigned short, h);
}
__device__ __forceinline__ float bf2f(unsigned short u) {
    return __builtin_bit_cast(float, (unsigned)u << 16);
}

// ---------------------------------------------------------------------------
// Kernel 1: partial Gram via bf16 MFMA (register-direct, statically indexed —
// rule #20). Channel sums via ones-fragment MFMAs. (256,3): measured best —
// (256,4) regressed in round 8 (L1/L2 thrash at 4 blocks/CU).
// ---------------------------------------------------------------------------
__global__ __launch_bounds__(256, 3) void gram_mfma(const float* __restrict__ x,
                                                    float* __restrict__ part,
                                                    int nchunk, int chunk_m) {
    int blk = blockIdx.x;
    int b = blk / nchunk, chunk = blk - b * nchunk;
    int t = threadIdx.x, w = t >> 6, l = t & 63;
    int lr = l & 15, lg = l >> 4;
    int mwave = chunk_m >> 2;          // m per wave
    int nck = mwave >> 5;              // 32-m chunks per wave (always even)

    const float* xw = x + (size_t)b * CH * MM + (size_t)chunk * chunk_m +
                      (size_t)w * mwave + lg * 8;
    const float* rp0 = xw + (size_t)(lr)      * MM;
    const float* rp1 = xw + (size_t)(16 + lr) * MM;
    const float* rp2 = xw + (size_t)(32 + lr) * MM;
    const float* rp3 = xw + (size_t)(48 + lr) * MM;

    f32x4 acc[10];
    f32x4 accs[4];                     // ones-MFMA channel-sum accumulators
    const f32x4 zero = {0.f, 0.f, 0.f, 0.f};
#pragma unroll
    for (int i = 0; i < 10; ++i) acc[i] = zero;
#pragma unroll
    for (int i = 0; i < 4; ++i) accs[i] = zero;

    s16x8 ones;
    {
        unsigned short* op1 = (unsigned short*)&ones;
#pragma unroll
        for (int i = 0; i < 8; ++i) op1[i] = 0x3F80;   // bf16 1.0
    }

    float4 A0, A1, A2, A3, A4, A5, A6, A7;
    float4 B0, B1, B2, B3, B4, B5, B6, B7;

#define LOAD8(P, o) do {                                                      \
        P##0 = *(const float4*)(rp0 + (o));  P##1 = *(const float4*)(rp0 + (o) + 4); \
        P##2 = *(const float4*)(rp1 + (o));  P##3 = *(const float4*)(rp1 + (o) + 4); \
        P##4 = *(const float4*)(rp2 + (o));  P##5 = *(const float4*)(rp2 + (o) + 4); \
        P##6 = *(const float4*)(rp3 + (o));  P##7 = *(const float4*)(rp3 + (o) + 4); \
    } while (0)

#define CVT_ROW(va, vb, fr) do {                                              \
        unsigned short* fp = (unsigned short*)&(fr);                          \
        fp[0] = f2bf((va).x); fp[1] = f2bf((va).y);                           \
        fp[2] = f2bf((va).z); fp[3] = f2bf((va).w);                           \
        fp[4] = f2bf((vb).x); fp[5] = f2bf((vb).y);                           \
        fp[6] = f2bf((vb).z); fp[7] = f2bf((vb).w);                           \
    } while (0)

#define COMPUTE(P) do {                                                       \
        s16x8 fr0, fr1, fr2, fr3;                                             \
        CVT_ROW(P##0, P##1, fr0);                                             \
        CVT_ROW(P##2, P##3, fr1);                                             \
        CVT_ROW(P##4, P##5, fr2);                                             \
        CVT_ROW(P##6, P##7, fr3);                                             \
        acc[0] = __builtin_amdgcn_mfma_f32_16x16x32_bf16(fr0, fr0, acc[0], 0, 0, 0); \
        acc[1] = __builtin_amdgcn_mfma_f32_16x16x32_bf16(fr0, fr1, acc[1], 0, 0, 0); \
        acc[2] = __builtin_amdgcn_mfma_f32_16x16x32_bf16(fr0, fr2, acc[2], 0, 0, 0); \
        acc[3] = __builtin_amdgcn_mfma_f32_16x16x32_bf16(fr0, fr3, acc[3], 0, 0, 0); \
        acc[4] = __builtin_amdgcn_mfma_f32_16x16x32_bf16(fr1, fr1, acc[4], 0, 0, 0); \
        acc[5] = __builtin_amdgcn_mfma_f32_16x16x32_bf16(fr1, fr2, acc[5], 0, 0, 0); \
        acc[6] = __builtin_amdgcn_mfma_f32_16x16x32_bf16(fr1, fr3, acc[6], 0, 0, 0); \
        acc[7] = __builtin_amdgcn_mfma_f32_16x16x32_bf16(fr2, fr2, acc[7], 0, 0, 0); \
        acc[8] = __builtin_amdgcn_mfma_f32_16x16x32_bf16(fr2, fr3, acc[8], 0, 0, 0); \
        acc[9] = __builtin_amdgcn_mfma_f32_16x16x32_bf16(fr3, fr3, acc[9], 0, 0, 0); \
        accs[0] = __builtin_amdgcn_mfma_f32_16x16x32_bf16(ones, fr0, accs[0], 0, 0, 0); \
        accs[1] = __builtin_amdgcn_mfma_f32_16x16x32_bf16(ones, fr1, accs[1], 0, 0, 0); \
        accs[2] = __builtin_amdgcn_mfma_f32_16x16x32_bf16(ones, fr2, accs[2], 0, 0, 0); \
        accs[3] = __builtin_amdgcn_mfma_f32_16x16x32_bf16(ones, fr3, accs[3], 0, 0, 0); \
    } while (0)

    LOAD8(A, 0);
    for (int c = 0; c < nck; c += 2) {
        LOAD8(B, (c + 1) * 32);
        COMPUTE(A);
        if (c + 2 < nck) LOAD8(A, (c + 2) * 32);
        COMPUTE(B);
    }

#define UIDX(i, j) ((i) * 4 + (j) - ((i) * ((i) + 1)) / 2)

    // cross-wave reduction via LDS (only upper tiles stored)
    __shared__ float xs[64 * 65];
    __shared__ float csum[64];
    for (int ww = 0; ww < 4; ++ww) {
        if (w == ww) {
#pragma unroll
            for (int i = 0; i < 4; ++i)
#pragma unroll
                for (int j = 0; j < 4; ++j)
                    if (i <= j) {
#pragma unroll
                        for (int jj = 0; jj < 4; ++jj) {
                            int r = i * 16 + lg * 4 + jj, cc = j * 16 + lr;
                            float v = acc[UIDX(i, j)][jj];
                            if (ww == 0) xs[r * 65 + cc] = v;
                            else         xs[r * 65 + cc] += v;
                        }
                    }
            if (l < 16) {
                if (ww == 0) {
                    csum[l]      = accs[0][0]; csum[16 + l] = accs[1][0];
                    csum[32 + l] = accs[2][0]; csum[48 + l] = accs[3][0];
                } else {
                    csum[l]      += accs[0][0]; csum[16 + l] += accs[1][0];
                    csum[32 + l] += accs[2][0]; csum[48 + l] += accs[3][0];
                }
            }
        }
        __syncthreads();
    }

    float* op = part + (size_t)blk * PSTRIDE;
#pragma unroll
    for (int rix = 0; rix < 16; ++rix) {
        int e = t + rix * 256;
        int r = e >> 6, cc = e & 63;
        float v = ((r >> 4) > (cc >> 4)) ? xs[cc * 65 + r] : xs[r * 65 + cc];
        __builtin_nontemporal_store(v, op + e);
    }
    if (t < 64) __builtin_nontemporal_store(csum[t], op + 4096 + t);
}

// ---------------------------------------------------------------------------
// Kernel 1b: reduce nchunk partials -> one 4160-float block per batch
// ---------------------------------------------------------------------------
__global__ __launch_bounds__(256) void reduce_parts(const float* __restrict__ part,
                                                    float* __restrict__ red,
                                                    int nchunk) {
    int b = blockIdx.y;
    int i = blockIdx.x * 256 + threadIdx.x;      // float4 index, 1040 total
    if (i >= PSTRIDE / 4) return;
    const f32x4* p = reinterpret_cast<const f32x4*>(part + (size_t)b * nchunk * PSTRIDE) + i;
    f32x4 s = {0.f, 0.f, 0.f, 0.f};
    for (int ch = 0; ch < nchunk; ++ch) {
        f32x4 v = __builtin_nontemporal_load(p + (size_t)ch * (PSTRIDE / 4));
        s += v;
    }
    reinterpret_cast<f32x4*>(red + (size_t)b * PSTRIDE)[i] = s;
}

// ---------------------------------------------------------------------------
// Kernel 2: cov -> Newton-Schulz(5) -> FC -> att.  Now 512 threads (8 waves):
// each wave computes a 16x32 slice of each 64x64 matmul (2 C-tiles, 12 MFMAs
// vs 24), staging and elementwise passes split over 512 threads — halves the
// latency-bound critical path of this serial 16-block kernel.
// ---------------------------------------------------------------------------
__device__ __forceinline__ void cvt_store(const float* __restrict__ M, int row,
                                          int col, unsigned short* Hp,
                                          unsigned short* Lp) {
    float4 v = *reinterpret_cast<const float4*>(M + row * SF + col);
    ushort4 h, lo;
    h.x = f2bf(v.x); lo.x = f2bf(v.x - bf2f(h.x));
    h.y = f2bf(v.y); lo.y = f2bf(v.y - bf2f(h.y));
    h.z = f2bf(v.z); lo.z = f2bf(v.z - bf2f(h.z));
    h.w = f2bf(v.w); lo.w = f2bf(v.w - bf2f(h.w));
    int byte = (row * 128 + col * 2) ^ ((row & 7) << 4);
    *reinterpret_cast<ushort4*>(reinterpret_cast<char*>(Hp) + byte) = h;
    *reinterpret_cast<ushort4*>(reinterpret_cast<char*>(Lp) + byte) = lo;
}

template <int EPI>   // 0: C=acc   1: C = (r==c?1.5:0) - 0.5*acc
__device__ __forceinline__ void mm64(const float* __restrict__ A,
                                     const float* __restrict__ B,
                                     float* __restrict__ C,
                                     unsigned short* AHp, unsigned short* ALp,
                                     unsigned short* BHp, unsigned short* BLp,
                                     int t) {
    int w = t >> 6, l = t & 63, lg = l >> 4, lr = l & 15;
    int wr = w & 3, wc = w >> 2;           // row-tile, column-half of this wave
    __syncthreads();                       // operands (f32) ready
#pragma unroll
    for (int r = 0; r < 2; ++r) {
        int e4 = t + r * 512;              // 1024 float4 = 4096 elements
        int row = e4 >> 4;                 // 16 float4 per row
        int col = (e4 & 15) << 2;
        cvt_store(A, row, col, AHp, ALp);
        cvt_store(B, row, col, BHp, BLp);
    }
    __syncthreads();
    f32x4 acc[2];
    const f32x4 zero = {0.f, 0.f, 0.f, 0.f};
    acc[0] = zero; acc[1] = zero;
    int arow = wr * 16 + lr;
#pragma unroll
    for (int kk = 0; kk < 2; ++kk) {
        int kbyte = kk * 64 + lg * 16;
        int abyte = (arow * 128 + kbyte) ^ ((arow & 7) << 4);
        s16x8 ah = *reinterpret_cast<const s16x8*>(reinterpret_cast<const char*>(AHp) + abyte);
        s16x8 al = *reinterpret_cast<const s16x8*>(reinterpret_cast<const char*>(ALp) + abyte);
#pragma unroll
        for (int ci = 0; ci < 2; ++ci) {
            int brow = (wc * 2 + ci) * 16 + lr;
            int bbyte = (brow * 128 + kbyte) ^ ((brow & 7) << 4);
            s16x8 bh = *reinterpret_cast<const s16x8*>(reinterpret_cast<const char*>(BHp) + bbyte);
            s16x8 bl = *reinterpret_cast<const s16x8*>(reinterpret_cast<const char*>(BLp) + bbyte);
            acc[ci] = __builtin_amdgcn_mfma_f32_16x16x32_bf16(ah, bh, acc[ci], 0, 0, 0);
            acc[ci] = __builtin_amdgcn_mfma_f32_16x16x32_bf16(ah, bl, acc[ci], 0, 0, 0);
            acc[ci] = __builtin_amdgcn_mfma_f32_16x16x32_bf16(al, bh, acc[ci], 0, 0, 0);
        }
    }
#pragma unroll
    for (int ci = 0; ci < 2; ++ci)
#pragma unroll
        for (int j = 0; j < 4; ++j) {
            int r = wr * 16 + lg * 4 + j, c = (wc * 2 + ci) * 16 + lr;
            float v = acc[ci][j];
            if (EPI == 1) v = (r == c ? 1.5f : 0.f) - 0.5f * v;
            C[r * SF + c] = v;
        }
    __syncthreads();                       // result visible
}

// dst[i] = sum_j M[j][i] * (src ? src[j] : 1)   (M symmetric; 8 waves)
__device__ __forceinline__ void mv64(float* __restrict__ dst,
                                     const float* __restrict__ M,
                                     const float* __restrict__ src,
                                     float* __restrict__ mvp, int t) {
    int i = t & 63, q = t >> 6;            // q = 0..7
    float p = 0.f;
#pragma unroll
    for (int jj = 0; jj < 8; ++jj) {
        int j = q * 8 + jj;
        float s = src ? src[j] : 1.f;
        p = fmaf(M[j * SF + i], s, p);
    }
    mvp[q * 64 + i] = p;
    __syncthreads();
    if (t < 64) {
        float s = ((mvp[t] + mvp[64 + t]) + (mvp[128 + t] + mvp[192 + t])) +
                  ((mvp[256 + t] + mvp[320 + t]) + (mvp[384 + t] + mvp[448 + t]));
        dst[t] = s;
    }
    __syncthreads();
}

__global__ __launch_bounds__(512) void ns_att(const float* __restrict__ red,
                                              const float* __restrict__ w1,
                                              const float* __restrict__ b1,
                                              const float* __restrict__ w2,
                                              const float* __restrict__ b2,
                                              float* __restrict__ att) {
    __shared__ float BUF[5][64 * SF];
    __shared__ unsigned short AH[64 * 64], AL[64 * 64], BH[64 * 64], BL[64 * 64];
    __shared__ float sv[64], u4s[64], vecA[64], vecB[64];
    __shared__ float mvp[512];
    __shared__ float hid8[8];
    __shared__ float scal[2];

    int b = blockIdx.x, t = threadIdx.x;
    const float* pb = red + (size_t)b * PSTRIDE;

    if (t < 64) sv[t] = pb[4096 + t];
    __syncthreads();

    // cov (unscaled) -> BUF0
    const float invM = 1.0f / (float)MM;
    const float invM2 = invM * invM;
#pragma unroll
    for (int r = 0; r < 2; ++r) {
        int e4 = t + r * 512;
        int row = e4 >> 4;
        int col = (e4 & 15) << 2;
        float4 g = *(reinterpret_cast<const float4*>(pb) + e4);
        float sr = sv[row] * invM2;
        BUF[0][row * SF + col]     = g.x * invM - sr * sv[col];
        BUF[0][row * SF + col + 1] = g.y * invM - sr * sv[col + 1];
        BUF[0][row * SF + col + 2] = g.z * invM - sr * sv[col + 2];
        BUF[0][row * SF + col + 3] = g.w * invM - sr * sv[col + 3];
    }
    __syncthreads();

    // trace via wave-0 shuffle reduction
    if (t < 64) {
        float d = BUF[0][t * SF + t];
#pragma unroll
        for (int m = 1; m < 64; m <<= 1) d += __shfl_xor(d, m);
        if (t == 0) { scal[0] = 1.0f / d; scal[1] = sqrtf(d); }
    }
    __syncthreads();
    float itr = scal[0];

    // A = cov/tr -> BUF0 ; ZY0 = 1.5I - 0.5A -> BUF1  (fused pass)
#pragma unroll
    for (int rr = 0; rr < 8; ++rr) {
        int e = t + rr * 512;
        int r = e >> 6, c = e & 63;
        float a = BUF[0][r * SF + c] * itr;
        BUF[0][r * SF + c] = a;
        BUF[1][r * SF + c] = (r == c ? 1.5f : 0.f) - 0.5f * a;
    }

    // 8 matmuls (Z1 = ZY0 = BUF1)
    mm64<0>(BUF[0], BUF[1], BUF[2], AH, AL, BH, BL, t);  // Y1 = A@ZY0
    mm64<1>(BUF[1], BUF[2], BUF[3], AH, AL, BH, BL, t);  // ZY1 = 1.5I-0.5 Z1@Y1
    mm64<0>(BUF[2], BUF[3], BUF[4], AH, AL, BH, BL, t);  // Y2 = Y1@ZY1
    mm64<0>(BUF[3], BUF[1], BUF[0], AH, AL, BH, BL, t);  // Z2 = ZY1@Z1
    mm64<1>(BUF[0], BUF[4], BUF[1], AH, AL, BH, BL, t);  // ZY2 = 1.5I-0.5 Z2@Y2
    mm64<0>(BUF[4], BUF[1], BUF[2], AH, AL, BH, BL, t);  // Y3 = Y2@ZY2
    mm64<0>(BUF[1], BUF[0], BUF[3], AH, AL, BH, BL, t);  // Z3 = ZY2@Z2
    mm64<1>(BUF[3], BUF[2], BUF[0], AH, AL, BH, BL, t);  // ZY3 = 1.5I-0.5 Z3@Y3
    // live: Y3 = BUF2, Z3 = BUF3, ZY3 = BUF0

    mv64(vecA, BUF[2], nullptr, mvp, t);   // u3 = 1^T Y3
    mv64(u4s,  BUF[0], vecA,    mvp, t);   // u4 = u3@ZY3
    mv64(vecA, BUF[0], u4s,     mvp, t);   // p  = u4@ZY3
    mv64(vecB, BUF[3], vecA,    mvp, t);   // q  = p@Z3    (= u4@Z4)
    mv64(vecA, BUF[2], vecB,    mvp, t);   // r  = q@Y3
    mv64(vecB, BUF[0], vecA,    mvp, t);   // s  = r@ZY3   (= u4@Z4@Y4)

    if (t < 64) sv[t] = (1.5f * u4s[t] - 0.5f * vecB[t]) * scal[1] * (1.0f / 64.0f);
    __syncthreads();
    if (t < 8) {
        float h = b1[t];
        for (int c = 0; c < 64; ++c) h += sv[c] * w1[t * 64 + c];
        hid8[t] = h > 0.f ? h : 0.f;
    }
    __syncthreads();
    if (t < 64) {
        float p = b2[t];
        for (int h = 0; h < 8; ++h) p += hid8[h] * w2[t * 8 + h];
        att[b * 64 + t] = 1.0f / (1.0f + expf(-p));
    }
}

// ---------------------------------------------------------------------------
// Kernel 3: out = att*x.  Reversed block-granularity traversal (L3 holds the
// tail of x after gram's forward sweep); nt stores. (round-6 exact)
// ---------------------------------------------------------------------------
__global__ __launch_bounds__(256) void scale_out(const float* __restrict__ x,
                                                 const float* __restrict__ att,
                                                 float* __restrict__ out) {
    const size_t total4 = (size_t)BATCH * CH * MM / 4;    // 16,777,216
    const size_t stride = (size_t)gridDim.x * blockDim.x; // 1,048,576 (16 iters)
    const f32x4* x4 = reinterpret_cast<const f32x4*>(x);
    f32x4* o4 = reinterpret_cast<f32x4*>(out);
    size_t base = (size_t)(gridDim.x - 1 - blockIdx.x) * blockDim.x + threadIdx.x;
    int niter = (int)(total4 / stride);
    size_t i = base + (size_t)(niter - 1) * stride;
    for (int k = 0; k < niter; ++k) {
        int bc = (int)(i >> 14);        // MM/4 = 16384 float4 per channel
        float a = att[bc];
        f32x4 v = x4[i];
        v *= a;
        __builtin_nontemporal_store(v, o4 + i);
        i -= stride;
    }
}

// ---------------------------------------------------------------------------
extern "C" void kernel_launch(void* const* d_in, const int* in_sizes, int n_in,
                              void* d_out, int out_size, void* d_ws, size_t ws_size,
                              hipStream_t stream) {
    const float* x  = (const float*)d_in[0];
    const float* w1 = (const float*)d_in[1];
    const float* b1 = (const float*)d_in[2];
    const float* w2 = (const float*)d_in[3];
    const float* b2 = (const float*)d_in[4];
    float* out = (float*)d_out;
    float* ws  = (float*)d_ws;

    int nchunk = 64;
    for (;;) {
        size_t need = ((size_t)BATCH * nchunk * PSTRIDE + (size_t)BATCH * PSTRIDE +
                       (size_t)BATCH * CH) * sizeof(float);
        if (need <= ws_size || nchunk == 1) break;
        nchunk >>= 1;
    }
    int chunk_m = MM / nchunk;

    float* part = ws;
    float* red  = ws + (size_t)BATCH * nchunk * PSTRIDE;
    float* att  = red + (size_t)BATCH * PSTRIDE;

    gram_mfma<<<BATCH * nchunk, 256, 0, stream>>>(x, part, nchunk, chunk_m);
    reduce_parts<<<dim3((PSTRIDE / 4 + 255) / 256, BATCH), 256, 0, stream>>>(part, red, nchunk);
    ns_att<<<512 / 512 * BATCH, 512, 0, stream>>>(red, w1, b1, w2, b2, att);
    scale_out<<<4096, 256, 0, stream>>>(x, att, out);
}